// Round 3
// baseline (113.865 us; speedup 1.0000x reference)
//
#include <hip/hip_runtime.h>

// MultiAgentLinearLayer via bf16 MFMA, round 5: 2 blocks/CU phase pipelining.
// out[b,o] = sum_k W[agent[b],o,k]*x[b,k] + bias[agent[b],o]
// B=2048, I=O=512, 64 agents, fp32 in/out. Threshold 5.97e-2 permits bf16.
//
// Round-5 restructure (from R2 evidence: kernel slice ~21.5us vs ~11us BW
// floor; 1 block/CU serialized compact->stage->K-loop phases, W stream idle
// outside the K-loop):
//  - block = 256 threads = 4 waves; BN=64 (wave w owns cols w*16..w*16+15,
//    FULL K=512). Grid = 8 n-tiles x 64 agents = 512 blocks = 2/CU.
//  - No k-split => no Rs LDS (34KB freed), no park barrier, no reduction.
//    LDS = rowlist 8KB + Xs 65KB = 73KB => two blocks co-resident; one
//    block's staging overlaps the other's W stream (phase pipelining).
//  - W streamed global->registers, 4-deep float4x2 prefetch primed at kernel
//    top (128B/lane, ~16MB machine-wide in flight over compaction+staging).
//  - X staged once to LDS as bf16 (stride 520, conflict-free b128 reads).
//  - fp32->bf16 via v_cvt_pk_bf16_f32 (scalar __bf16 casts), RNE.
//  - nfrag guard: skip dead 16-row A-frags (count~32 => nfrag=2 of 4).
//  - XCD swizzle: agent a's 8 n-tile blocks share bid%8 => same XCD; X rows
//    L2-hot across its blocks (8 agents x 64KB X per 4MB XCD L2).
//  - 2 barriers per chunk, typically 1 chunk (count<=64).

constexpr int BATCH  = 2048;
constexpr int NAGENT = 64;
constexpr int IN_F   = 512;
constexpr int OUT_F  = 512;

constexpr int BN  = 64;         // block n-tile (4 waves x 16 cols)
constexpr int MCH = 64;         // m rows per chunk
constexpr int XS  = IN_F + 8;   // X LDS stride in bf16 elems (520)

typedef __attribute__((ext_vector_type(8))) short short8;     // bf16 A/B frag
typedef __attribute__((ext_vector_type(4))) float f32x4;      // fp32 C/D frag
typedef __attribute__((ext_vector_type(4))) unsigned int u32x4;
typedef __bf16 bf16x2 __attribute__((ext_vector_type(2)));

__device__ inline unsigned pk_bf(float lo, float hi) {
  bf16x2 v;
  v[0] = (__bf16)lo;
  v[1] = (__bf16)hi;
  return __builtin_bit_cast(unsigned, v);   // v_cvt_pk_bf16_f32, RNE
}

__global__ __launch_bounds__(256, 2) void agent_linear_mfma5(
    const int*   __restrict__ which,
    const float* __restrict__ x,
    const float* __restrict__ weight,
    const float* __restrict__ bias,
    float*       __restrict__ out) {
  const int tid  = threadIdx.x;
  const int lane = tid & 63;
  const int wid  = tid >> 6;         // 0..3 (n-wave)

  // bid = (a&7) + 8*nt + 64*(a>>3): agent a's 8 n-tiles share bid%8 (XCD)
  const int bid   = blockIdx.x;      // 0..511
  const int agent = (bid & 7) | ((bid >> 6) << 3);
  const int obase = ((bid >> 3) & 7) * BN;

  __shared__ int wsum_s[4];
  __shared__ int rowlist_s[BATCH];                       // 8 KB
  __shared__ __align__(16) unsigned short Xs[MCH * XS];  // 65 KB bf16

  const int nl = lane & 15;      // n within frag / m within A-frag
  const int kq = lane >> 4;      // k-quad 0..3

  const float* wp = weight + ((size_t)(agent * OUT_F + obase + wid * 16 + nl)) * IN_F
                  + kq * 8;

  // ---- prime 4-deep W prefetch NOW: HBM latency hides under compact+stage ----
  float4 pa[4], pb[4];
#pragma unroll
  for (int j = 0; j < 4; ++j) {
    pa[j] = *(const float4*)(wp + j * 32);
    pb[j] = *(const float4*)(wp + j * 32 + 4);
  }

  const float bv = bias[agent * OUT_F + obase + wid * 16 + nl];

  // ---- stable compaction: rows with which[i]==agent, ascending ----
  // 256 threads x 8 values each (two int4 loads, 32B/lane)
  const int4* w4p = (const int4*)which;
  int4 v0 = w4p[2 * tid];
  int4 v1 = w4p[2 * tid + 1];
  int m0_ = (v0.x == agent), m1_ = (v0.y == agent), m2_ = (v0.z == agent),
      m3_ = (v0.w == agent), m4_ = (v1.x == agent), m5_ = (v1.y == agent),
      m6_ = (v1.z == agent), m7_ = (v1.w == agent);
  int lc = m0_ + m1_ + m2_ + m3_ + m4_ + m5_ + m6_ + m7_;
  int s = lc;
#pragma unroll
  for (int off = 1; off < 64; off <<= 1) {
    int t = __shfl_up(s, off);
    if (lane >= off) s += t;
  }
  if (lane == 63) wsum_s[wid] = s;
  __syncthreads();
  int base = 0, count = 0;
#pragma unroll
  for (int w = 0; w < 4; ++w) {
    int ws = wsum_s[w];
    if (w < wid) base += ws;
    count += ws;
  }
  {
    int pos = base + s - lc;
    int i0 = 8 * tid;
    if (m0_) rowlist_s[pos++] = i0;
    if (m1_) rowlist_s[pos++] = i0 + 1;
    if (m2_) rowlist_s[pos++] = i0 + 2;
    if (m3_) rowlist_s[pos++] = i0 + 3;
    if (m4_) rowlist_s[pos++] = i0 + 4;
    if (m5_) rowlist_s[pos++] = i0 + 5;
    if (m6_) rowlist_s[pos++] = i0 + 6;
    if (m7_) rowlist_s[pos]   = i0 + 7;
  }

  for (int m0 = 0; m0 < count; m0 += MCH) {
    const int mcount = min(MCH, count - m0);
    const int nfrag  = (mcount + 15) >> 4;   // live 16-row A-frags (1..4)

    __syncthreads();   // iter0: rowlist ready; later: prior Xs reads done

    // ---- stage X chunk (live rows only): r = 2t + (tid>>7), c4 = tid&127 ----
    {
      const int rh = tid >> 7;          // 0/1
      const int c4 = tid & 127;
#pragma unroll 4
      for (int t = 0; 2 * t < mcount; ++t) {
        int r = 2 * t + rh;
        if (r < mcount) {
          float4 xv = *(const float4*)(x + (size_t)rowlist_s[m0 + r] * IN_F + c4 * 4);
          uint2 w2;
          w2.x = pk_bf(xv.x, xv.y);
          w2.y = pk_bf(xv.z, xv.w);
          *(uint2*)&Xs[r * XS + c4 * 4] = w2;
        }
      }
    }
    __syncthreads();   // Xs ready

    // ---- barrier-free K-loop: full K=512, 16 iters, 4-deep prefetch ----
    f32x4 acc[4] = {{0.f,0.f,0.f,0.f},{0.f,0.f,0.f,0.f},
                    {0.f,0.f,0.f,0.f},{0.f,0.f,0.f,0.f}};
#pragma unroll
    for (int k = 0; k < 16; ++k) {
      float4 c0 = pa[k & 3], c1 = pb[k & 3];
      if (k + 4 < 16) {
        pa[k & 3] = *(const float4*)(wp + (k + 4) * 32);
        pb[k & 3] = *(const float4*)(wp + (k + 4) * 32 + 4);
      }
      u32x4 q;
      q[0] = pk_bf(c0.x, c0.y); q[1] = pk_bf(c0.z, c0.w);
      q[2] = pk_bf(c1.x, c1.y); q[3] = pk_bf(c1.z, c1.w);
      short8 bfr = __builtin_bit_cast(short8, q);
#pragma unroll
      for (int i = 0; i < 4; ++i) {
        if (i < nfrag) {   // wave-uniform: skip dead-row frags
          short8 af = *(const short8*)&Xs[(i * 16 + nl) * XS + k * 32 + kq * 8];
          acc[i] = __builtin_amdgcn_mfma_f32_16x16x32_bf16(af, bfr, acc[i], 0, 0, 0);
        }
      }
    }

    // ---- epilogue: D row=(lane>>4)*4+reg (=m), col=lane&15 (=n) ----
#pragma unroll
    for (int i = 0; i < 4; ++i) {
      if (i < nfrag) {
#pragma unroll
        for (int r = 0; r < 4; ++r) {
          int m = i * 16 + kq * 4 + r;
          if (m < mcount) {
            out[(size_t)rowlist_s[m0 + m] * OUT_F + obase + wid * 16 + nl] =
                acc[i][r] + bv;
          }
        }
      }
    }

    if (m0 + MCH < count) {   // re-prime for (rare) next chunk; L2-hot
#pragma unroll
      for (int j = 0; j < 4; ++j) {
        pa[j] = *(const float4*)(wp + j * 32);
        pb[j] = *(const float4*)(wp + j * 32 + 4);
      }
    }
  }
}

extern "C" void kernel_launch(void* const* d_in, const int* in_sizes, int n_in,
                              void* d_out, int out_size, void* d_ws, size_t ws_size,
                              hipStream_t stream) {
  const int*   which = (const int*)d_in[0];
  const float* x     = (const float*)d_in[1];
  const float* w     = (const float*)d_in[2];
  const float* b     = (const float*)d_in[3];
  float*       out   = (float*)d_out;

  dim3 grid(OUT_F / BN * NAGENT);   // 8 x 64 = 512 blocks, 2 per CU
  agent_linear_mfma5<<<grid, dim3(256), 0, stream>>>(which, x, w, b, out);
}

// Round 4
// 104.892 us; speedup vs baseline: 1.0855x; 1.0855x over previous
//
#include <hip/hip_runtime.h>

// MultiAgentLinearLayer via bf16 MFMA, round 6: R4 structure (proven 104.6us)
// + 6-deep W prime (2x in-flight) + earliest `which` issue.
// out[b,o] = sum_k W[agent[b],o,k]*x[b,k] + bias[agent[b],o]
// B=2048, I=O=512, 64 agents, fp32 in/out. Threshold 5.97e-2 permits bf16.
//
// R5 (2 blocks/CU) regressed +9us: lockstep co-resident blocks gave no phase
// overlap, doubled per-agent compact/stage redundancy, halved waves/SIMD.
// Reverted. R6 deltas vs R4:
//  - W prefetch primed 6-deep at kernel top (192B/lane, ~197KB/CU = 77% of
//    the W tile in flight) so compaction+staging are fully covered by the
//    stream; K-loop only issues 2 residual prefetches (k=0,1) then drains.
//  - `which` int2 load issued first (longest dep chain: load->scan->rowlist
//    ->X gathers).
// Everything else identical to R4: 16 waves, kh-split + Rs reduction, XCD
// swizzle, cvt_pk packing, nfrag guard, stride-520 Xs.

constexpr int BATCH  = 2048;
constexpr int NAGENT = 64;
constexpr int IN_F   = 512;
constexpr int OUT_F  = 512;

constexpr int BN  = 128;        // block n-tile
constexpr int MCH = 64;         // m rows per chunk (count<=64 in practice)
constexpr int XS  = IN_F + 8;   // X LDS stride in bf16 elems (520)

typedef __attribute__((ext_vector_type(8))) short short8;     // bf16 A/B frag
typedef __attribute__((ext_vector_type(4))) float f32x4;      // fp32 C/D frag
typedef __attribute__((ext_vector_type(4))) unsigned int u32x4;
typedef __bf16 bf16x2 __attribute__((ext_vector_type(2)));

__device__ inline unsigned pk_bf(float lo, float hi) {
  bf16x2 v;
  v[0] = (__bf16)lo;
  v[1] = (__bf16)hi;
  return __builtin_bit_cast(unsigned, v);   // v_cvt_pk_bf16_f32, RNE
}

__global__ __launch_bounds__(1024, 4) void agent_linear_mfma6(
    const int*   __restrict__ which,
    const float* __restrict__ x,
    const float* __restrict__ weight,
    const float* __restrict__ bias,
    float*       __restrict__ out) {
  const int tid   = threadIdx.x;
  const int lane  = tid & 63;
  const int wid   = tid >> 6;        // 0..15
  const int w8    = wid & 7;         // n-wave within BN
  const int kh    = wid >> 3;        // k-half: 0 or 1

  // bid = (a&7) + 8*n + 32*(a>>3): agent a's 4 n-tiles all share bid%8
  const int bid   = blockIdx.x;      // 0..255
  const int agent = (bid & 7) | ((bid >> 5) << 3);
  const int obase = ((bid >> 3) & 3) * BN;

  __shared__ int rowlist_s[BATCH];                       // 8 KB
  __shared__ int wsum_s[16];
  __shared__ __align__(16) unsigned short Xs[MCH * XS];  // 65 KB bf16
  __shared__ float Rs[8][MCH][17];                       // 34 KB, k-half partials

  // ---- issue `which` load FIRST: longest dependent chain ----
  int2 v = ((const int2*)which)[tid];                    // 2 vals/thread

  const int nl = lane & 15;      // n within frag / m within A-frag
  const int kq = lane >> 4;      // k-quad 0..3

  const float* wp = weight + ((size_t)(agent * OUT_F + obase + w8 * 16 + nl)) * IN_F
                  + kh * 256 + kq * 8;

  // ---- prime 6-deep W prefetch: ~197KB/CU in flight covers compact+stage ----
  float4 pa[6], pb[6];
#pragma unroll
  for (int j = 0; j < 6; ++j) {
    pa[j] = *(const float4*)(wp + j * 32);
    pb[j] = *(const float4*)(wp + j * 32 + 4);
  }

  const float bv = bias[agent * OUT_F + obase + w8 * 16 + nl];

  // ---- stable compaction: rows with which[i]==agent, ascending ----
  int lc = (v.x == agent) + (v.y == agent);
  int s = lc;
#pragma unroll
  for (int off = 1; off < 64; off <<= 1) {
    int t = __shfl_up(s, off);
    if (lane >= off) s += t;
  }
  if (lane == 63) wsum_s[wid] = s;
  __syncthreads();
  int base = 0, count = 0;
#pragma unroll
  for (int w = 0; w < 16; ++w) {
    int ws = wsum_s[w];
    if (w < wid) base += ws;
    count += ws;
  }
  {
    int pos = base + s - lc;
    if (v.x == agent) rowlist_s[pos++] = 2 * tid;
    if (v.y == agent) rowlist_s[pos]   = 2 * tid + 1;
  }
  __syncthreads();   // rowlist ready

  for (int m0 = 0; m0 < count; m0 += MCH) {
    const int mcount = min(MCH, count - m0);
    const int nfrag  = (mcount + 15) >> 4;   // live 16-row A-frags (1..4)

    // ---- stage X chunk: live rows only ----
#pragma unroll
    for (int t = 0; t < 8; ++t) {
      int idx = t * 1024 + tid;
      int r   = idx >> 7;          // 0..63 (wave-uniform per t)
      int c4  = idx & 127;         // float4 column
      if (r < mcount) {
        float4 xv = *(const float4*)(x + (size_t)rowlist_s[m0 + r] * IN_F + c4 * 4);
        uint2 w2;
        w2.x = pk_bf(xv.x, xv.y);
        w2.y = pk_bf(xv.z, xv.w);
        *(uint2*)&Xs[r * XS + c4 * 4] = w2;
      }
    }
    __syncthreads();   // Xs ready

    // ---- barrier-free K-loop over this wave's 256-k half ----
    f32x4 acc[4] = {{0.f,0.f,0.f,0.f},{0.f,0.f,0.f,0.f},
                    {0.f,0.f,0.f,0.f},{0.f,0.f,0.f,0.f}};
    const int kbase = kh * 256;
#pragma unroll
    for (int k = 0; k < 8; ++k) {
      float4 c0 = pa[k % 6], c1 = pb[k % 6];
      if (k + 6 < 8) {   // only k=0,1 issue residual prefetches
        pa[k % 6] = *(const float4*)(wp + (k + 6) * 32);
        pb[k % 6] = *(const float4*)(wp + (k + 6) * 32 + 4);
      }
      u32x4 q;
      q[0] = pk_bf(c0.x, c0.y); q[1] = pk_bf(c0.z, c0.w);
      q[2] = pk_bf(c1.x, c1.y); q[3] = pk_bf(c1.z, c1.w);
      short8 bfr = __builtin_bit_cast(short8, q);
#pragma unroll
      for (int i = 0; i < 4; ++i) {
        if (i < nfrag) {   // wave-uniform: skip dead-row frags entirely
          short8 af = *(const short8*)&Xs[(i * 16 + nl) * XS + kbase + k * 32 + kq * 8];
          acc[i] = __builtin_amdgcn_mfma_f32_16x16x32_bf16(af, bfr, acc[i], 0, 0, 0);
        }
      }
    }

    // ---- cross-k-half reduction: upper waves park partials in LDS ----
    if (kh == 1) {
#pragma unroll
      for (int i = 0; i < 4; ++i)
        if (i < nfrag)
#pragma unroll
          for (int r = 0; r < 4; ++r)
            Rs[w8][i * 16 + kq * 4 + r][nl] = acc[i][r];
    }
    __syncthreads();   // Rs ready; all Xs reads of this chunk also complete

    // ---- epilogue by lower waves: D row=(lane>>4)*4+reg, col=lane&15 ----
    if (kh == 0) {
#pragma unroll
      for (int i = 0; i < 4; ++i) {
        if (i < nfrag) {
#pragma unroll
          for (int r = 0; r < 4; ++r) {
            int m = i * 16 + kq * 4 + r;
            if (m < mcount) {
              out[(size_t)rowlist_s[m0 + m] * OUT_F + obase + w8 * 16 + nl] =
                  acc[i][r] + Rs[w8][m][nl] + bv;
            }
          }
        }
      }
    }

    if (m0 + MCH < count) {   // re-prime for the (rare) next chunk; L2-hot
#pragma unroll
      for (int j = 0; j < 6; ++j) {
        pa[j] = *(const float4*)(wp + j * 32);
        pb[j] = *(const float4*)(wp + j * 32 + 4);
      }
    }
  }
}

extern "C" void kernel_launch(void* const* d_in, const int* in_sizes, int n_in,
                              void* d_out, int out_size, void* d_ws, size_t ws_size,
                              hipStream_t stream) {
  const int*   which = (const int*)d_in[0];
  const float* x     = (const float*)d_in[1];
  const float* w     = (const float*)d_in[2];
  const float* b     = (const float*)d_in[3];
  float*       out   = (float*)d_out;

  dim3 grid(OUT_F / BN * NAGENT);   // 256 blocks, 1 per CU (swizzled decode)
  agent_linear_mfma6<<<grid, dim3(1024), 0, stream>>>(which, x, w, b, out);
}